// Round 2
// baseline (3012.406 us; speedup 1.0000x reference)
//
#include <hip/hip_runtime.h>

#define N_NODES 100000
#define N_EDGES 3200000
#define N_PAIRS 1000000

#define BUCK_SHIFT 9
#define BUCK_NODES 512                       // nodes per bucket
#define NBUCK ((N_NODES + BUCK_NODES - 1) / BUCK_NODES)   // 196
#define CH 8192                              // edges per binning block
#define NCHB ((N_EDGES + CH - 1) / CH)       // 391

// ---------------- bucket build ----------------

__global__ void k_zero(int* __restrict__ p, int n) {
  int i = blockIdx.x * blockDim.x + threadIdx.x;
  if (i < n) p[i] = 0;
}

// count bucket sizes: per-block LDS hist -> one global atomic per bin per block
__global__ void __launch_bounds__(256) k_bucket_count(
    const int* __restrict__ dst, int* __restrict__ bucket_cnt)
{
  __shared__ int hist[NBUCK];
  int t = threadIdx.x;
  int lo = blockIdx.x * CH;
  int hi = lo + CH; if (hi > N_EDGES) hi = N_EDGES;
  for (int i = t; i < NBUCK; i += 256) hist[i] = 0;
  __syncthreads();
  for (int e = lo + t; e < hi; e += 256) atomicAdd(&hist[dst[e] >> BUCK_SHIFT], 1);
  __syncthreads();
  for (int i = t; i < NBUCK; i += 256) if (hist[i]) atomicAdd(&bucket_cnt[i], hist[i]);
}

// exclusive scan of 196 bucket counts (single block)
__global__ void k_bucket_scan(const int* __restrict__ cnt,
                              int* __restrict__ base, int* __restrict__ woff)
{
  __shared__ int sh[256];
  int t = threadIdx.x;
  int v = (t < NBUCK) ? cnt[t] : 0;
  sh[t] = v;
  __syncthreads();
  for (int off = 1; off < 256; off <<= 1) {
    int u = (t >= off) ? sh[t - off] : 0;
    __syncthreads();
    sh[t] += u;
    __syncthreads();
  }
  if (t < NBUCK) {
    int excl = sh[t] - v;
    base[t] = excl;
    woff[t] = excl;
    if (t == NBUCK - 1) base[NBUCK] = sh[t];
  }
}

// bin edges into bucket_data as packed (src<<9 | dst&511); per-block LDS hist
// reserves a contiguous run per bin -> dense line-filling writes.
__global__ void __launch_bounds__(256) k_binning(
    const int* __restrict__ src, const int* __restrict__ dst,
    int* __restrict__ bucket_woff, int* __restrict__ bucket_data)
{
  __shared__ int hist[NBUCK];
  __shared__ int rbase[NBUCK];
  __shared__ int roff[NBUCK];
  int t = threadIdx.x;
  int lo = blockIdx.x * CH;
  int hi = lo + CH; if (hi > N_EDGES) hi = N_EDGES;
  for (int i = t; i < NBUCK; i += 256) { hist[i] = 0; roff[i] = 0; }
  __syncthreads();
  for (int e = lo + t; e < hi; e += 256) atomicAdd(&hist[dst[e] >> BUCK_SHIFT], 1);
  __syncthreads();
  for (int i = t; i < NBUCK; i += 256)
    rbase[i] = hist[i] ? atomicAdd(&bucket_woff[i], hist[i]) : 0;
  __syncthreads();
  for (int e = lo + t; e < hi; e += 256) {
    int d = dst[e];
    int b = d >> BUCK_SHIFT;
    int r = atomicAdd(&roff[b], 1);
    bucket_data[rbase[b] + r] = (src[e] << BUCK_SHIFT) | (d & (BUCK_NODES - 1));
  }
}

// ---------------- fused SAGE layers (block = bucket, acc in LDS) ----------------

// layer 1: F_in=32 -> F_out=64. Half-wave (32 lanes) per edge.
__global__ void __launch_bounds__(1024) k_sage1(
    const float* __restrict__ x, const int* __restrict__ bucket_base,
    const int* __restrict__ bucket_data,
    const float* __restrict__ Wl, const float* __restrict__ bl,
    const float* __restrict__ Wr, float* __restrict__ out)
{
  __shared__ float acc[BUCK_NODES * 32];
  __shared__ int degl[BUCK_NODES];
  int blk = blockIdx.x;
  int t = threadIdx.x;
  int lane = t & 63;
  int wid = t >> 6;                 // 0..15
  int f = lane & 31;
  int half = lane >> 5;

  for (int i = t; i < BUCK_NODES * 32; i += 1024) acc[i] = 0.f;
  for (int i = t; i < BUCK_NODES; i += 1024) degl[i] = 0;
  __syncthreads();

  int base = bucket_base[blk];
  int cnt = bucket_base[blk + 1] - base;
  const int* bd = bucket_data + base;
  int tpos = wid * 2 + half;        // 0..31

  int i = tpos;
  for (; i + 96 < cnt; i += 128) {
    int v0 = bd[i], v1 = bd[i + 32], v2 = bd[i + 64], v3 = bd[i + 96];
    float a0 = x[(v0 >> BUCK_SHIFT) * 32 + f];
    float a1 = x[(v1 >> BUCK_SHIFT) * 32 + f];
    float a2 = x[(v2 >> BUCK_SHIFT) * 32 + f];
    float a3 = x[(v3 >> BUCK_SHIFT) * 32 + f];
    atomicAdd(&acc[(v0 & (BUCK_NODES - 1)) * 32 + f], a0);
    atomicAdd(&acc[(v1 & (BUCK_NODES - 1)) * 32 + f], a1);
    atomicAdd(&acc[(v2 & (BUCK_NODES - 1)) * 32 + f], a2);
    atomicAdd(&acc[(v3 & (BUCK_NODES - 1)) * 32 + f], a3);
    if (f == 0) {
      atomicAdd(&degl[v0 & (BUCK_NODES - 1)], 1);
      atomicAdd(&degl[v1 & (BUCK_NODES - 1)], 1);
      atomicAdd(&degl[v2 & (BUCK_NODES - 1)], 1);
      atomicAdd(&degl[v3 & (BUCK_NODES - 1)], 1);
    }
  }
  for (; i < cnt; i += 32) {
    int v = bd[i];
    float a = x[(v >> BUCK_SHIFT) * 32 + f];
    atomicAdd(&acc[(v & (BUCK_NODES - 1)) * 32 + f], a);
    if (f == 0) atomicAdd(&degl[v & (BUCK_NODES - 1)], 1);
  }
  __syncthreads();

  // epilogue: mean + shfl-GEMM + ReLU; wave per node
  int node0 = blk * BUCK_NODES;
  int nn = N_NODES - node0; if (nn > BUCK_NODES) nn = BUCK_NODES;
  for (int nloc = wid; nloc < nn; nloc += 16) {
    int n = node0 + nloc;
    int deg = degl[nloc];
    float invd = (deg > 0) ? 1.f / (float)deg : 0.f;
    float meanv = acc[nloc * 32 + f] * invd;
    float selfv = x[n * 32 + f];
    float a = bl[lane];
#pragma unroll
    for (int f2 = 0; f2 < 32; ++f2) {
      a = fmaf(__shfl(meanv, f2), Wl[f2 * 64 + lane], a);
      a = fmaf(__shfl(selfv, f2), Wr[f2 * 64 + lane], a);
    }
    out[n * 64 + lane] = fmaxf(a, 0.f);
  }
}

// layer 2: F_in=64 -> F_out=64. Full wave per edge.
__global__ void __launch_bounds__(1024) k_sage2(
    const float* __restrict__ hin, const int* __restrict__ bucket_base,
    const int* __restrict__ bucket_data,
    const float* __restrict__ Wl, const float* __restrict__ bl,
    const float* __restrict__ Wr, float* __restrict__ out)
{
  __shared__ float acc[BUCK_NODES * 64];
  __shared__ int degl[BUCK_NODES];
  int blk = blockIdx.x;
  int t = threadIdx.x;
  int lane = t & 63;
  int wid = t >> 6;                 // 0..15

  for (int i = t; i < BUCK_NODES * 64; i += 1024) acc[i] = 0.f;
  for (int i = t; i < BUCK_NODES; i += 1024) degl[i] = 0;
  __syncthreads();

  int base = bucket_base[blk];
  int cnt = bucket_base[blk + 1] - base;
  const int* bd = bucket_data + base;

  int i = wid;
  for (; i + 48 < cnt; i += 64) {
    int v0 = bd[i], v1 = bd[i + 16], v2 = bd[i + 32], v3 = bd[i + 48];
    float a0 = hin[(v0 >> BUCK_SHIFT) * 64 + lane];
    float a1 = hin[(v1 >> BUCK_SHIFT) * 64 + lane];
    float a2 = hin[(v2 >> BUCK_SHIFT) * 64 + lane];
    float a3 = hin[(v3 >> BUCK_SHIFT) * 64 + lane];
    atomicAdd(&acc[(v0 & (BUCK_NODES - 1)) * 64 + lane], a0);
    atomicAdd(&acc[(v1 & (BUCK_NODES - 1)) * 64 + lane], a1);
    atomicAdd(&acc[(v2 & (BUCK_NODES - 1)) * 64 + lane], a2);
    atomicAdd(&acc[(v3 & (BUCK_NODES - 1)) * 64 + lane], a3);
    if (lane == 0) {
      atomicAdd(&degl[v0 & (BUCK_NODES - 1)], 1);
      atomicAdd(&degl[v1 & (BUCK_NODES - 1)], 1);
      atomicAdd(&degl[v2 & (BUCK_NODES - 1)], 1);
      atomicAdd(&degl[v3 & (BUCK_NODES - 1)], 1);
    }
  }
  for (; i < cnt; i += 16) {
    int v = bd[i];
    float a = hin[(v >> BUCK_SHIFT) * 64 + lane];
    atomicAdd(&acc[(v & (BUCK_NODES - 1)) * 64 + lane], a);
    if (lane == 0) atomicAdd(&degl[v & (BUCK_NODES - 1)], 1);
  }
  __syncthreads();

  int node0 = blk * BUCK_NODES;
  int nn = N_NODES - node0; if (nn > BUCK_NODES) nn = BUCK_NODES;
  for (int nloc = wid; nloc < nn; nloc += 16) {
    int n = node0 + nloc;
    int deg = degl[nloc];
    float invd = (deg > 0) ? 1.f / (float)deg : 0.f;
    float meanv = acc[nloc * 64 + lane] * invd;
    float selfv = hin[n * 64 + lane];
    float a = bl[lane];
#pragma unroll
    for (int f2 = 0; f2 < 64; ++f2) {
      a = fmaf(__shfl(meanv, f2), Wl[f2 * 64 + lane], a);
      a = fmaf(__shfl(selfv, f2), Wr[f2 * 64 + lane], a);
    }
    out[n * 64 + lane] = fmaxf(a, 0.f);
  }
}

// ---------------- edge scorer: wave = 8 edges, 8 lanes/edge ----------------

__global__ void __launch_bounds__(256) k_edge(
    const float* __restrict__ h, const int* __restrict__ pairs,
    const float* __restrict__ Wh, const float* __restrict__ bh,
    float* __restrict__ out)
{
  int gid = blockIdx.x * blockDim.x + threadIdx.x;
  int wave = gid >> 6;
  int lane = threadIdx.x & 63;
  int j = lane >> 3, c = lane & 7;
  int e = wave * 8 + j;
  if (e >= N_PAIRS) return;
  int sN = pairs[2 * e];
  int dN = pairs[2 * e + 1];
  const float4* hs = (const float4*)(h + sN * 64 + c * 8);
  const float4* hd = (const float4*)(h + dN * 64 + c * 8);
  float4 a0 = hs[0], a1 = hs[1];
  float4 b0 = hd[0], b1 = hd[1];
  const float4* wsp = (const float4*)(Wh + c * 8);
  float4 w0 = wsp[0], w1 = wsp[1];
  const float4* wdp = (const float4*)(Wh + 64 + c * 8);
  float4 w2 = wdp[0], w3 = wdp[1];
  float acc = a0.x * w0.x + a0.y * w0.y + a0.z * w0.z + a0.w * w0.w
            + a1.x * w1.x + a1.y * w1.y + a1.z * w1.z + a1.w * w1.w
            + b0.x * w2.x + b0.y * w2.y + b0.z * w2.z + b0.w * w2.w
            + b1.x * w3.x + b1.y * w3.y + b1.z * w3.z + b1.w * w3.w;
  acc += __shfl_xor(acc, 1);
  acc += __shfl_xor(acc, 2);
  acc += __shfl_xor(acc, 4);
  if (c == 0) out[e] = acc + bh[0];
}

// ---------------- launch ----------------

extern "C" void kernel_launch(void* const* d_in, const int* in_sizes, int n_in,
                              void* d_out, int out_size, void* d_ws, size_t ws_size,
                              hipStream_t stream)
{
  const float* x   = (const float*)d_in[0];
  const int*   ei  = (const int*)d_in[1];
  const int* pairs = (const int*)d_in[2];
  const float* Wl1 = (const float*)d_in[3];
  const float* bl1 = (const float*)d_in[4];
  const float* Wr1 = (const float*)d_in[5];
  const float* Wl2 = (const float*)d_in[6];
  const float* bl2 = (const float*)d_in[7];
  const float* Wr2 = (const float*)d_in[8];
  const float* Wh  = (const float*)d_in[9];
  const float* bh  = (const float*)d_in[10];
  float* out = (float*)d_out;

  const int* src = ei;             // edge_index[0]
  const int* dst = ei + N_EDGES;   // edge_index[1]

  char* p = (char*)d_ws;
  auto alloc = [&](size_t bytes) {
    char* r = p;
    p += (bytes + 255) & ~(size_t)255;
    return r;
  };
  int*   bucket_cnt  = (int*)alloc(256 * 4);
  int*   bucket_base = (int*)alloc(257 * 4);
  int*   bucket_woff = (int*)alloc(256 * 4);
  int*   bucket_data = (int*)alloc((size_t)N_EDGES * 4);
  float* h1          = (float*)alloc((size_t)N_NODES * 64 * 4);
  float* h2          = (float*)alloc((size_t)N_NODES * 64 * 4);

  k_zero<<<1, 256, 0, stream>>>(bucket_cnt, NBUCK);
  k_bucket_count<<<NCHB, 256, 0, stream>>>(dst, bucket_cnt);
  k_bucket_scan<<<1, 256, 0, stream>>>(bucket_cnt, bucket_base, bucket_woff);
  k_binning<<<NCHB, 256, 0, stream>>>(src, dst, bucket_woff, bucket_data);

  k_sage1<<<NBUCK, 1024, 0, stream>>>(x,  bucket_base, bucket_data, Wl1, bl1, Wr1, h1);
  k_sage2<<<NBUCK, 1024, 0, stream>>>(h1, bucket_base, bucket_data, Wl2, bl2, Wr2, h2);
  k_edge<<<(N_PAIRS * 8) / 256, 256, 0, stream>>>(h2, pairs, Wh, bh, out);
}

// Round 3
// 368.135 us; speedup vs baseline: 8.1829x; 8.1829x over previous
//
#include <hip/hip_runtime.h>

#define N_NODES 100000
#define N_EDGES 3200000
#define N_PAIRS 1000000

#define BUCK_SHIFT 9
#define BUCK_NODES 512                                     // nodes per bucket
#define NBUCK ((N_NODES + BUCK_NODES - 1) / BUCK_NODES)    // 196
#define CH 8192                                            // edges per binning block
#define NCHB ((N_EDGES + CH - 1) / CH)                     // 391

// ---------------- bucket build (two-level counting sort -> CSR) ----------------

__global__ void k_zero(int* __restrict__ p, int n) {
  int i = blockIdx.x * blockDim.x + threadIdx.x;
  if (i < n) p[i] = 0;
}

__global__ void __launch_bounds__(256) k_bucket_count(
    const int* __restrict__ dst, int* __restrict__ bucket_cnt)
{
  __shared__ int hist[NBUCK];
  int t = threadIdx.x;
  int lo = blockIdx.x * CH;
  int hi = lo + CH; if (hi > N_EDGES) hi = N_EDGES;
  for (int i = t; i < NBUCK; i += 256) hist[i] = 0;
  __syncthreads();
  for (int e = lo + t; e < hi; e += 256) atomicAdd(&hist[dst[e] >> BUCK_SHIFT], 1);
  __syncthreads();
  for (int i = t; i < NBUCK; i += 256) if (hist[i]) atomicAdd(&bucket_cnt[i], hist[i]);
}

__global__ void k_bucket_scan(const int* __restrict__ cnt,
                              int* __restrict__ base, int* __restrict__ woff)
{
  __shared__ int sh[256];
  int t = threadIdx.x;
  int v = (t < NBUCK) ? cnt[t] : 0;
  sh[t] = v;
  __syncthreads();
  for (int off = 1; off < 256; off <<= 1) {
    int u = (t >= off) ? sh[t - off] : 0;
    __syncthreads();
    sh[t] += u;
    __syncthreads();
  }
  if (t < NBUCK) {
    int excl = sh[t] - v;
    base[t] = excl;
    woff[t] = excl;
    if (t == NBUCK - 1) base[NBUCK] = sh[t];
  }
}

// bin edges as packed (src<<9 | dst&511); per-block LDS hist reserves a
// contiguous run per bucket -> dense line-filling writes.
__global__ void __launch_bounds__(256) k_binning(
    const int* __restrict__ src, const int* __restrict__ dst,
    int* __restrict__ bucket_woff, int* __restrict__ bucket_data)
{
  __shared__ int hist[NBUCK];
  __shared__ int rbase[NBUCK];
  __shared__ int roff[NBUCK];
  int t = threadIdx.x;
  int lo = blockIdx.x * CH;
  int hi = lo + CH; if (hi > N_EDGES) hi = N_EDGES;
  for (int i = t; i < NBUCK; i += 256) { hist[i] = 0; roff[i] = 0; }
  __syncthreads();
  for (int e = lo + t; e < hi; e += 256) atomicAdd(&hist[dst[e] >> BUCK_SHIFT], 1);
  __syncthreads();
  for (int i = t; i < NBUCK; i += 256)
    rbase[i] = hist[i] ? atomicAdd(&bucket_woff[i], hist[i]) : 0;
  __syncthreads();
  for (int e = lo + t; e < hi; e += 256) {
    int d = dst[e];
    int b = d >> BUCK_SHIFT;
    int r = atomicAdd(&roff[b], 1);
    bucket_data[rbase[b] + r] = (src[e] << BUCK_SHIFT) | (d & (BUCK_NODES - 1));
  }
}

// per-bucket counting sort: bucket_data (L2-hot, read 2x) -> csr + row_ptr.
// Random csr writes land inside a ~65KB L2-resident window -> full lines.
__global__ void __launch_bounds__(512) k_bucket_csr(
    const int* __restrict__ bucket_base, const int* __restrict__ bucket_data,
    int* __restrict__ csr, int* __restrict__ row_ptr)
{
  __shared__ int hist[BUCK_NODES];
  __shared__ int sc[BUCK_NODES];
  __shared__ int offs[BUCK_NODES];
  int b = blockIdx.x;
  int t = threadIdx.x;
  int bbase = bucket_base[b];
  int cnt = bucket_base[b + 1] - bbase;
  const int* bd = bucket_data + bbase;
  hist[t] = 0;
  __syncthreads();
  for (int i = t; i < cnt; i += 512) atomicAdd(&hist[bd[i] & (BUCK_NODES - 1)], 1);
  __syncthreads();
  int v = hist[t];
  sc[t] = v;
  __syncthreads();
  for (int off = 1; off < 512; off <<= 1) {
    int u = (t >= off) ? sc[t - off] : 0;
    __syncthreads();
    sc[t] += u;
    __syncthreads();
  }
  int start = bbase + sc[t] - v;                 // exclusive
  offs[t] = start;
  int node = b * BUCK_NODES + t;
  if (node <= N_NODES) row_ptr[node] = start;    // node==N_NODES -> row_ptr end
  __syncthreads();
  for (int i = t; i < cnt; i += 512) {
    int pv = bd[i];
    int pos = atomicAdd(&offs[pv & (BUCK_NODES - 1)], 1);
    csr[pos] = pv >> BUCK_SHIFT;
  }
}

// ---------------- SAGE layers (R1 structure: 1 wave per node, no LDS) --------

// layer 1: F_in=32, F_out=64. f = lane&31; half = lane>>5 takes every other nbr.
__global__ void __launch_bounds__(256) k_layer1(
    const float* __restrict__ x, const int* __restrict__ row_ptr,
    const int* __restrict__ csr, const float* __restrict__ Wl,
    const float* __restrict__ bl, const float* __restrict__ Wr,
    float* __restrict__ out)
{
  int gid = blockIdx.x * blockDim.x + threadIdx.x;
  int n = gid >> 6;
  int lane = threadIdx.x & 63;
  if (n >= N_NODES) return;
  int f = lane & 31;
  int half = lane >> 5;
  int beg = row_ptr[n], end = row_ptr[n + 1];
  int deg = end - beg;
  float s = 0.f;
  int i = beg + half;
  for (; i + 6 < end; i += 8) {
    int i0 = csr[i], i1 = csr[i + 2], i2 = csr[i + 4], i3 = csr[i + 6];
    s += x[i0 * 32 + f];
    s += x[i1 * 32 + f];
    s += x[i2 * 32 + f];
    s += x[i3 * 32 + f];
  }
  for (; i < end; i += 2) s += x[csr[i] * 32 + f];
  s += __shfl_xor(s, 32);
  float mean = (deg > 0) ? s / (float)deg : 0.f;
  float self = x[n * 32 + f];
  float acc = bl[lane];
#pragma unroll
  for (int f2 = 0; f2 < 32; ++f2) {
    acc = fmaf(__shfl(mean, f2), Wl[f2 * 64 + lane], acc);
    acc = fmaf(__shfl(self, f2), Wr[f2 * 64 + lane], acc);
  }
  out[n * 64 + lane] = fmaxf(acc, 0.f);
}

// layer 2 fused with the edge-scorer projection: h2 never materialized.
// u[n] = dot(relu_row, Wh[0:64]), v[n] = dot(relu_row, Wh[64:128]).
__global__ void __launch_bounds__(256) k_layer2uv(
    const float* __restrict__ hin, const int* __restrict__ row_ptr,
    const int* __restrict__ csr, const float* __restrict__ Wl,
    const float* __restrict__ bl, const float* __restrict__ Wr,
    const float* __restrict__ Wh,
    float* __restrict__ u, float* __restrict__ v)
{
  int gid = blockIdx.x * blockDim.x + threadIdx.x;
  int n = gid >> 6;
  int lane = threadIdx.x & 63;
  if (n >= N_NODES) return;
  int beg = row_ptr[n], end = row_ptr[n + 1];
  int deg = end - beg;
  float s = 0.f;
  int i = beg;
  for (; i + 3 < end; i += 4) {
    int i0 = csr[i], i1 = csr[i + 1], i2 = csr[i + 2], i3 = csr[i + 3];
    s += hin[i0 * 64 + lane];
    s += hin[i1 * 64 + lane];
    s += hin[i2 * 64 + lane];
    s += hin[i3 * 64 + lane];
  }
  for (; i < end; ++i) s += hin[csr[i] * 64 + lane];
  float mean = (deg > 0) ? s / (float)deg : 0.f;
  float self = hin[n * 64 + lane];
  float acc = bl[lane];
#pragma unroll
  for (int ff = 0; ff < 64; ++ff) {
    acc = fmaf(__shfl(mean, ff), Wl[ff * 64 + lane], acc);
    acc = fmaf(__shfl(self, ff), Wr[ff * 64 + lane], acc);
  }
  float r = fmaxf(acc, 0.f);
  float pu = r * Wh[lane];
  float pv = r * Wh[64 + lane];
#pragma unroll
  for (int off = 1; off < 64; off <<= 1) {
    pu += __shfl_xor(pu, off);
    pv += __shfl_xor(pv, off);
  }
  if (lane == 0) { u[n] = pu; v[n] = pv; }
}

// ---------------- edge scorer: table lookup only ----------------

__global__ void __launch_bounds__(256) k_edge_lite(
    const int* __restrict__ pairs, const float* __restrict__ u,
    const float* __restrict__ v, const float* __restrict__ bh,
    float* __restrict__ out)
{
  int e = blockIdx.x * blockDim.x + threadIdx.x;
  if (e < N_PAIRS) {
    int sN = pairs[2 * e];
    int dN = pairs[2 * e + 1];
    out[e] = u[sN] + v[dN] + bh[0];
  }
}

// ---------------- launch ----------------

extern "C" void kernel_launch(void* const* d_in, const int* in_sizes, int n_in,
                              void* d_out, int out_size, void* d_ws, size_t ws_size,
                              hipStream_t stream)
{
  const float* x   = (const float*)d_in[0];
  const int*   ei  = (const int*)d_in[1];
  const int* pairs = (const int*)d_in[2];
  const float* Wl1 = (const float*)d_in[3];
  const float* bl1 = (const float*)d_in[4];
  const float* Wr1 = (const float*)d_in[5];
  const float* Wl2 = (const float*)d_in[6];
  const float* bl2 = (const float*)d_in[7];
  const float* Wr2 = (const float*)d_in[8];
  const float* Wh  = (const float*)d_in[9];
  const float* bh  = (const float*)d_in[10];
  float* out = (float*)d_out;

  const int* src = ei;             // edge_index[0]
  const int* dst = ei + N_EDGES;   // edge_index[1]

  char* p = (char*)d_ws;
  auto alloc = [&](size_t bytes) {
    char* r = p;
    p += (bytes + 255) & ~(size_t)255;
    return r;
  };
  int*   bucket_cnt  = (int*)alloc(256 * 4);
  int*   bucket_base = (int*)alloc(257 * 4);
  int*   bucket_woff = (int*)alloc(256 * 4);
  int*   bucket_data = (int*)alloc((size_t)N_EDGES * 4);
  int*   csr         = (int*)alloc((size_t)N_EDGES * 4);
  int*   row_ptr     = (int*)alloc((size_t)(N_NODES + 1) * 4);
  float* h1          = (float*)alloc((size_t)N_NODES * 64 * 4);
  float* uu          = (float*)alloc((size_t)N_NODES * 4);
  float* vv          = (float*)alloc((size_t)N_NODES * 4);

  k_zero<<<1, 256, 0, stream>>>(bucket_cnt, NBUCK);
  k_bucket_count<<<NCHB, 256, 0, stream>>>(dst, bucket_cnt);
  k_bucket_scan<<<1, 256, 0, stream>>>(bucket_cnt, bucket_base, bucket_woff);
  k_binning<<<NCHB, 256, 0, stream>>>(src, dst, bucket_woff, bucket_data);
  k_bucket_csr<<<NBUCK, 512, 0, stream>>>(bucket_base, bucket_data, csr, row_ptr);

  k_layer1<<<(N_NODES * 64) / 256, 256, 0, stream>>>(x, row_ptr, csr, Wl1, bl1, Wr1, h1);
  k_layer2uv<<<(N_NODES * 64) / 256, 256, 0, stream>>>(h1, row_ptr, csr, Wl2, bl2, Wr2, Wh, uu, vv);
  k_edge_lite<<<(N_PAIRS + 255) / 256, 256, 0, stream>>>(pairs, uu, vv, bh, out);
}

// Round 4
// 343.235 us; speedup vs baseline: 8.7765x; 1.0725x over previous
//
#include <hip/hip_runtime.h>

typedef unsigned int uint;
typedef unsigned short ushort;

#define N_NODES 100000
#define N_EDGES 3200000
#define N_PAIRS 1000000

#define BUCK_SHIFT 9
#define BUCK_NODES 512                                     // nodes per bucket
#define NBUCK ((N_NODES + BUCK_NODES - 1) / BUCK_NODES)    // 196
#define CH 8192                                            // edges per binning block
#define NCHB ((N_EDGES + CH - 1) / CH)                     // 391

__device__ __forceinline__ float bf_lo(uint u) { return __uint_as_float(u << 16); }
__device__ __forceinline__ float bf_hi(uint u) { return __uint_as_float(u & 0xFFFF0000u); }
__device__ __forceinline__ ushort f2bf(float f) {
  uint u = __float_as_uint(f);
  return (ushort)((u + 0x7FFF + ((u >> 16) & 1)) >> 16);   // round-nearest-even
}

// ---------------- bucket build (two-level counting sort -> CSR) ----------------

__global__ void k_zero(int* __restrict__ p, int n) {
  int i = blockIdx.x * blockDim.x + threadIdx.x;
  if (i < n) p[i] = 0;
}

__global__ void __launch_bounds__(256) k_bucket_count(
    const int* __restrict__ dst, int* __restrict__ bucket_cnt)
{
  __shared__ int hist[NBUCK];
  int t = threadIdx.x;
  int lo = blockIdx.x * CH;
  int hi = lo + CH; if (hi > N_EDGES) hi = N_EDGES;
  for (int i = t; i < NBUCK; i += 256) hist[i] = 0;
  __syncthreads();
  for (int e = lo + t; e < hi; e += 256) atomicAdd(&hist[dst[e] >> BUCK_SHIFT], 1);
  __syncthreads();
  for (int i = t; i < NBUCK; i += 256) if (hist[i]) atomicAdd(&bucket_cnt[i], hist[i]);
}

__global__ void k_bucket_scan(const int* __restrict__ cnt,
                              int* __restrict__ base, int* __restrict__ woff)
{
  __shared__ int sh[256];
  int t = threadIdx.x;
  int v = (t < NBUCK) ? cnt[t] : 0;
  sh[t] = v;
  __syncthreads();
  for (int off = 1; off < 256; off <<= 1) {
    int u = (t >= off) ? sh[t - off] : 0;
    __syncthreads();
    sh[t] += u;
    __syncthreads();
  }
  if (t < NBUCK) {
    int excl = sh[t] - v;
    base[t] = excl;
    woff[t] = excl;
    if (t == NBUCK - 1) base[NBUCK] = sh[t];
  }
}

__global__ void __launch_bounds__(256) k_binning(
    const int* __restrict__ src, const int* __restrict__ dst,
    int* __restrict__ bucket_woff, int* __restrict__ bucket_data)
{
  __shared__ int hist[NBUCK];
  __shared__ int rbase[NBUCK];
  __shared__ int roff[NBUCK];
  int t = threadIdx.x;
  int lo = blockIdx.x * CH;
  int hi = lo + CH; if (hi > N_EDGES) hi = N_EDGES;
  for (int i = t; i < NBUCK; i += 256) { hist[i] = 0; roff[i] = 0; }
  __syncthreads();
  for (int e = lo + t; e < hi; e += 256) atomicAdd(&hist[dst[e] >> BUCK_SHIFT], 1);
  __syncthreads();
  for (int i = t; i < NBUCK; i += 256)
    rbase[i] = hist[i] ? atomicAdd(&bucket_woff[i], hist[i]) : 0;
  __syncthreads();
  for (int e = lo + t; e < hi; e += 256) {
    int d = dst[e];
    int b = d >> BUCK_SHIFT;
    int r = atomicAdd(&roff[b], 1);
    bucket_data[rbase[b] + r] = (src[e] << BUCK_SHIFT) | (d & (BUCK_NODES - 1));
  }
}

__global__ void __launch_bounds__(512) k_bucket_csr(
    const int* __restrict__ bucket_base, const int* __restrict__ bucket_data,
    int* __restrict__ csr, int* __restrict__ row_ptr)
{
  __shared__ int hist[BUCK_NODES];
  __shared__ int sc[BUCK_NODES];
  __shared__ int offs[BUCK_NODES];
  int b = blockIdx.x;
  int t = threadIdx.x;
  int bbase = bucket_base[b];
  int cnt = bucket_base[b + 1] - bbase;
  const int* bd = bucket_data + bbase;
  hist[t] = 0;
  __syncthreads();
  for (int i = t; i < cnt; i += 512) atomicAdd(&hist[bd[i] & (BUCK_NODES - 1)], 1);
  __syncthreads();
  int v = hist[t];
  sc[t] = v;
  __syncthreads();
  for (int off = 1; off < 512; off <<= 1) {
    int u = (t >= off) ? sc[t - off] : 0;
    __syncthreads();
    sc[t] += u;
    __syncthreads();
  }
  int start = bbase + sc[t] - v;                 // exclusive
  offs[t] = start;
  int node = b * BUCK_NODES + t;
  if (node <= N_NODES) row_ptr[node] = start;
  __syncthreads();
  for (int i = t; i < cnt; i += 512) {
    int pv = bd[i];
    int pos = atomicAdd(&offs[pv & (BUCK_NODES - 1)], 1);
    csr[pos] = pv >> BUCK_SHIFT;
  }
}

// ---------------- fp32 -> bf16 convert (for gather-side x) ----------------

__global__ void __launch_bounds__(256) k_cvt_bf16(
    const float* __restrict__ in, ushort* __restrict__ out, int n)
{
  int i = blockIdx.x * blockDim.x + threadIdx.x;
  if (i < n) out[i] = f2bf(in[i]);
}

// ---------------- SAGE layers: wave per node, bf16 gathers ----------------

// layer 1: F_in=32 -> F_out=64. Gather rows are 64B (32 bf16).
// lane = 16*q + c : q = neighbor slot (0..3), c = feature-pair (0..15).
__global__ void __launch_bounds__(256) k_layer1(
    const float* __restrict__ x, const uint* __restrict__ xb,   // xb row = 16 uints
    const int* __restrict__ row_ptr, const int* __restrict__ csr,
    const float* __restrict__ Wl, const float* __restrict__ bl,
    const float* __restrict__ Wr, ushort* __restrict__ h1b)
{
  int gid = blockIdx.x * blockDim.x + threadIdx.x;
  int n = gid >> 6;
  int lane = threadIdx.x & 63;
  if (n >= N_NODES) return;
  int q = lane >> 4;
  int c = lane & 15;
  int beg = row_ptr[n], end = row_ptr[n + 1];
  int deg = end - beg;
  float s0x = 0.f, s0y = 0.f, s1x = 0.f, s1y = 0.f;
  int i = beg;
  for (; i + 7 < end; i += 8) {                  // 8 neighbors/iter, 2 loads/lane
    int n0 = csr[i + q];
    int n1 = csr[i + 4 + q];
    uint u0 = xb[n0 * 16 + c];
    uint u1 = xb[n1 * 16 + c];
    s0x += bf_lo(u0); s0y += bf_hi(u0);
    s1x += bf_lo(u1); s1y += bf_hi(u1);
  }
  for (; i < end; i += 4) {
    if (i + q < end) {
      uint u0 = xb[csr[i + q] * 16 + c];
      s0x += bf_lo(u0); s0y += bf_hi(u0);
    }
  }
  float sx = s0x + s1x, sy = s0y + s1y;
  sx += __shfl_xor(sx, 16); sy += __shfl_xor(sy, 16);
  sx += __shfl_xor(sx, 32); sy += __shfl_xor(sy, 32);
  float invd = (deg > 0) ? 1.f / (float)deg : 0.f;
  float mx = sx * invd, my = sy * invd;          // features 2c (x), 2c+1 (y)
  float selfv = x[n * 32 + (lane & 31)];         // fp32 self, feature = lane&31
  float a0 = bl[lane], a1 = 0.f;
#pragma unroll
  for (int f2 = 0; f2 < 32; ++f2) {
    float mf = (f2 & 1) ? __shfl(my, f2 >> 1) : __shfl(mx, f2 >> 1);
    float sf = __shfl(selfv, f2);
    a0 = fmaf(mf, Wl[f2 * 64 + lane], a0);
    a1 = fmaf(sf, Wr[f2 * 64 + lane], a1);
  }
  float r = fmaxf(a0 + a1, 0.f);
  h1b[n * 64 + lane] = f2bf(r);
}

// layer 2 fused with edge projection: u[n]=dot(h2,Wh_lo), v[n]=dot(h2,Wh_hi).
// Gather rows are 128B (64 bf16). lane = 32*h + c : h = neighbor slot (0..1),
// c = feature-pair (0..31).
__global__ void __launch_bounds__(256) k_layer2uv(
    const uint* __restrict__ hb,                 // h1 bf16, row = 32 uints
    const int* __restrict__ row_ptr, const int* __restrict__ csr,
    const float* __restrict__ Wl, const float* __restrict__ bl,
    const float* __restrict__ Wr, const float* __restrict__ Wh,
    float* __restrict__ u, float* __restrict__ v)
{
  int gid = blockIdx.x * blockDim.x + threadIdx.x;
  int n = gid >> 6;
  int lane = threadIdx.x & 63;
  if (n >= N_NODES) return;
  int h = lane >> 5;
  int c = lane & 31;
  int beg = row_ptr[n], end = row_ptr[n + 1];
  int deg = end - beg;
  float s0x = 0.f, s0y = 0.f, s1x = 0.f, s1y = 0.f;
  float s2x = 0.f, s2y = 0.f, s3x = 0.f, s3y = 0.f;
  int i = beg;
  for (; i + 7 < end; i += 8) {                  // 8 neighbors/iter, 4 loads/lane
    int n0 = csr[i + h];
    int n1 = csr[i + 2 + h];
    int n2 = csr[i + 4 + h];
    int n3 = csr[i + 6 + h];
    uint u0 = hb[n0 * 32 + c];
    uint u1 = hb[n1 * 32 + c];
    uint u2 = hb[n2 * 32 + c];
    uint u3 = hb[n3 * 32 + c];
    s0x += bf_lo(u0); s0y += bf_hi(u0);
    s1x += bf_lo(u1); s1y += bf_hi(u1);
    s2x += bf_lo(u2); s2y += bf_hi(u2);
    s3x += bf_lo(u3); s3y += bf_hi(u3);
  }
  for (; i < end; i += 2) {
    if (i + h < end) {
      uint u0 = hb[csr[i + h] * 32 + c];
      s0x += bf_lo(u0); s0y += bf_hi(u0);
    }
  }
  float sx = (s0x + s1x) + (s2x + s3x);
  float sy = (s0y + s1y) + (s2y + s3y);
  sx += __shfl_xor(sx, 32); sy += __shfl_xor(sy, 32);
  float invd = (deg > 0) ? 1.f / (float)deg : 0.f;
  float mx = sx * invd, my = sy * invd;          // features 2c, 2c+1
  const ushort* hbs = (const ushort*)hb;
  float selfv = __uint_as_float(((uint)hbs[n * 64 + lane]) << 16);
  float a0 = bl[lane], a1 = 0.f;
#pragma unroll
  for (int f2 = 0; f2 < 64; ++f2) {
    float mf = (f2 & 1) ? __shfl(my, f2 >> 1) : __shfl(mx, f2 >> 1);
    float sf = __shfl(selfv, f2);
    a0 = fmaf(mf, Wl[f2 * 64 + lane], a0);
    a1 = fmaf(sf, Wr[f2 * 64 + lane], a1);
  }
  float r = fmaxf(a0 + a1, 0.f);
  float pu = r * Wh[lane];
  float pv = r * Wh[64 + lane];
#pragma unroll
  for (int off = 1; off < 64; off <<= 1) {
    pu += __shfl_xor(pu, off);
    pv += __shfl_xor(pv, off);
  }
  if (lane == 0) { u[n] = pu; v[n] = pv; }
}

// ---------------- edge scorer: table lookup only ----------------

__global__ void __launch_bounds__(256) k_edge_lite(
    const int* __restrict__ pairs, const float* __restrict__ u,
    const float* __restrict__ v, const float* __restrict__ bh,
    float* __restrict__ out)
{
  int e = blockIdx.x * blockDim.x + threadIdx.x;
  if (e < N_PAIRS) {
    int sN = pairs[2 * e];
    int dN = pairs[2 * e + 1];
    out[e] = u[sN] + v[dN] + bh[0];
  }
}

// ---------------- launch ----------------

extern "C" void kernel_launch(void* const* d_in, const int* in_sizes, int n_in,
                              void* d_out, int out_size, void* d_ws, size_t ws_size,
                              hipStream_t stream)
{
  const float* x   = (const float*)d_in[0];
  const int*   ei  = (const int*)d_in[1];
  const int* pairs = (const int*)d_in[2];
  const float* Wl1 = (const float*)d_in[3];
  const float* bl1 = (const float*)d_in[4];
  const float* Wr1 = (const float*)d_in[5];
  const float* Wl2 = (const float*)d_in[6];
  const float* bl2 = (const float*)d_in[7];
  const float* Wr2 = (const float*)d_in[8];
  const float* Wh  = (const float*)d_in[9];
  const float* bh  = (const float*)d_in[10];
  float* out = (float*)d_out;

  const int* src = ei;             // edge_index[0]
  const int* dst = ei + N_EDGES;   // edge_index[1]

  char* p = (char*)d_ws;
  auto alloc = [&](size_t bytes) {
    char* r = p;
    p += (bytes + 255) & ~(size_t)255;
    return r;
  };
  int*    bucket_cnt  = (int*)alloc(256 * 4);
  int*    bucket_base = (int*)alloc(257 * 4);
  int*    bucket_woff = (int*)alloc(256 * 4);
  int*    bucket_data = (int*)alloc((size_t)N_EDGES * 4);
  int*    csr         = (int*)alloc((size_t)N_EDGES * 4);
  int*    row_ptr     = (int*)alloc((size_t)(N_NODES + 1) * 4);
  ushort* xb          = (ushort*)alloc((size_t)N_NODES * 32 * 2);
  ushort* h1b         = (ushort*)alloc((size_t)N_NODES * 64 * 2);
  float*  uu          = (float*)alloc((size_t)N_NODES * 4);
  float*  vv          = (float*)alloc((size_t)N_NODES * 4);

  k_zero<<<1, 256, 0, stream>>>(bucket_cnt, NBUCK);
  k_bucket_count<<<NCHB, 256, 0, stream>>>(dst, bucket_cnt);
  k_bucket_scan<<<1, 256, 0, stream>>>(bucket_cnt, bucket_base, bucket_woff);
  k_binning<<<NCHB, 256, 0, stream>>>(src, dst, bucket_woff, bucket_data);
  k_bucket_csr<<<NBUCK, 512, 0, stream>>>(bucket_base, bucket_data, csr, row_ptr);
  k_cvt_bf16<<<(N_NODES * 32 + 255) / 256, 256, 0, stream>>>(x, xb, N_NODES * 32);

  k_layer1<<<(N_NODES * 64) / 256, 256, 0, stream>>>(
      x, (const uint*)xb, row_ptr, csr, Wl1, bl1, Wr1, h1b);
  k_layer2uv<<<(N_NODES * 64) / 256, 256, 0, stream>>>(
      (const uint*)h1b, row_ptr, csr, Wl2, bl2, Wr2, Wh, uu, vv);
  k_edge_lite<<<(N_PAIRS + 255) / 256, 256, 0, stream>>>(pairs, uu, vv, bh, out);
}

// Round 5
// 235.667 us; speedup vs baseline: 12.7825x; 1.4564x over previous
//
#include <hip/hip_runtime.h>

typedef unsigned int uint;
typedef unsigned short ushort;
typedef __attribute__((ext_vector_type(8))) short bf16x8;
typedef __attribute__((ext_vector_type(4))) float f32x4;

#define N_NODES 100000
#define N_EDGES 3200000
#define N_PAIRS 1000000
#define N_TILES (N_NODES / 16)                             // 6250 (exact)

#define BUCK_SHIFT 9
#define BUCK_NODES 512                                     // nodes per bucket
#define NBUCK ((N_NODES + BUCK_NODES - 1) / BUCK_NODES)    // 196
#define CH 8192                                            // edges per binning block
#define NCHB ((N_EDGES + CH - 1) / CH)                     // 391

__device__ __forceinline__ float bf_lo(uint u) { return __uint_as_float(u << 16); }
__device__ __forceinline__ float bf_hi(uint u) { return __uint_as_float(u & 0xFFFF0000u); }
__device__ __forceinline__ ushort f2bf(float f) {
  uint u = __float_as_uint(f);
  return (ushort)((u + 0x7FFF + ((u >> 16) & 1)) >> 16);   // round-nearest-even
}
__device__ __forceinline__ uint pack2bf(float lo, float hi) {
  return (uint)f2bf(lo) | ((uint)f2bf(hi) << 16);
}

// ---------------- bucket build (two-level counting sort -> CSR) ----------------

__global__ void k_zero(int* __restrict__ p, int n) {
  int i = blockIdx.x * blockDim.x + threadIdx.x;
  if (i < n) p[i] = 0;
}

__global__ void __launch_bounds__(256) k_bucket_count(
    const int* __restrict__ dst, int* __restrict__ bucket_cnt)
{
  __shared__ int hist[NBUCK];
  int t = threadIdx.x;
  int lo = blockIdx.x * CH;
  int hi = lo + CH; if (hi > N_EDGES) hi = N_EDGES;
  for (int i = t; i < NBUCK; i += 256) hist[i] = 0;
  __syncthreads();
  for (int e = lo + t; e < hi; e += 256) atomicAdd(&hist[dst[e] >> BUCK_SHIFT], 1);
  __syncthreads();
  for (int i = t; i < NBUCK; i += 256) if (hist[i]) atomicAdd(&bucket_cnt[i], hist[i]);
}

__global__ void k_bucket_scan(const int* __restrict__ cnt,
                              int* __restrict__ base, int* __restrict__ woff)
{
  __shared__ int sh[256];
  int t = threadIdx.x;
  int v = (t < NBUCK) ? cnt[t] : 0;
  sh[t] = v;
  __syncthreads();
  for (int off = 1; off < 256; off <<= 1) {
    int u = (t >= off) ? sh[t - off] : 0;
    __syncthreads();
    sh[t] += u;
    __syncthreads();
  }
  if (t < NBUCK) {
    int excl = sh[t] - v;
    base[t] = excl;
    woff[t] = excl;
    if (t == NBUCK - 1) base[NBUCK] = sh[t];
  }
}

__global__ void __launch_bounds__(256) k_binning(
    const int* __restrict__ src, const int* __restrict__ dst,
    int* __restrict__ bucket_woff, int* __restrict__ bucket_data)
{
  __shared__ int hist[NBUCK];
  __shared__ int rbase[NBUCK];
  __shared__ int roff[NBUCK];
  int t = threadIdx.x;
  int lo = blockIdx.x * CH;
  int hi = lo + CH; if (hi > N_EDGES) hi = N_EDGES;
  for (int i = t; i < NBUCK; i += 256) { hist[i] = 0; roff[i] = 0; }
  __syncthreads();
  for (int e = lo + t; e < hi; e += 256) atomicAdd(&hist[dst[e] >> BUCK_SHIFT], 1);
  __syncthreads();
  for (int i = t; i < NBUCK; i += 256)
    rbase[i] = hist[i] ? atomicAdd(&bucket_woff[i], hist[i]) : 0;
  __syncthreads();
  for (int e = lo + t; e < hi; e += 256) {
    int d = dst[e];
    int b = d >> BUCK_SHIFT;
    int r = atomicAdd(&roff[b], 1);
    bucket_data[rbase[b] + r] = (src[e] << BUCK_SHIFT) | (d & (BUCK_NODES - 1));
  }
}

__global__ void __launch_bounds__(512) k_bucket_csr(
    const int* __restrict__ bucket_base, const int* __restrict__ bucket_data,
    int* __restrict__ csr, int* __restrict__ row_ptr)
{
  __shared__ int hist[BUCK_NODES];
  __shared__ int sc[BUCK_NODES];
  __shared__ int offs[BUCK_NODES];
  int b = blockIdx.x;
  int t = threadIdx.x;
  int bbase = bucket_base[b];
  int cnt = bucket_base[b + 1] - bbase;
  const int* bd = bucket_data + bbase;
  hist[t] = 0;
  __syncthreads();
  for (int i = t; i < cnt; i += 512) atomicAdd(&hist[bd[i] & (BUCK_NODES - 1)], 1);
  __syncthreads();
  int v = hist[t];
  sc[t] = v;
  __syncthreads();
  for (int off = 1; off < 512; off <<= 1) {
    int u = (t >= off) ? sc[t - off] : 0;
    __syncthreads();
    sc[t] += u;
    __syncthreads();
  }
  int start = bbase + sc[t] - v;                 // exclusive
  offs[t] = start;
  int node = b * BUCK_NODES + t;
  if (node <= N_NODES) row_ptr[node] = start;
  __syncthreads();
  for (int i = t; i < cnt; i += 512) {
    int pv = bd[i];
    int pos = atomicAdd(&offs[pv & (BUCK_NODES - 1)], 1);
    csr[pos] = pv >> BUCK_SHIFT;
  }
}

// ---------------- prep: fp32 -> bf16 conversions ----------------

__global__ void __launch_bounds__(256) k_cvt_bf16(
    const float* __restrict__ in, ushort* __restrict__ out, int n)
{
  int i = blockIdx.x * blockDim.x + threadIdx.x;
  if (i < n) out[i] = f2bf(in[i]);
}

// W1T[col][f] (64x64) from Wl1/Wr1; W2T[col][f] (64x128) from Wl2/Wr2.
// Stored K-contiguous so B-fragments are one dwordx4 each.
__global__ void __launch_bounds__(256) k_prep_w(
    const float* __restrict__ Wl1, const float* __restrict__ Wr1,
    const float* __restrict__ Wl2, const float* __restrict__ Wr2,
    ushort* __restrict__ W1T, ushort* __restrict__ W2T)
{
  int t = blockIdx.x * blockDim.x + threadIdx.x;
  if (t < 4096) {
    int col = t >> 6, f = t & 63;
    float w = (f < 32) ? Wl1[f * 64 + col] : Wr1[(f - 32) * 64 + col];
    W1T[col * 64 + f] = f2bf(w);
  }
  if (t < 8192) {
    int col = t >> 7, f = t & 127;
    float w = (f < 64) ? Wl2[f * 64 + col] : Wr2[(f - 64) * 64 + col];
    W2T[col * 128 + f] = f2bf(w);
  }
}

// ---------------- gather-mean kernels (wave per node, dwordx4 gathers) -------

// layer 1 mean: xb rows are 64B (4 uint4). lane: slot=(l>>2) in 0..15 neighbor,
// fq=(l&3) feature-quad (8 bf16). 16 neighbors in flight per instruction.
__global__ void __launch_bounds__(256) k_gather1(
    const uint4* __restrict__ xb4, const int* __restrict__ row_ptr,
    const int* __restrict__ csr, uint4* __restrict__ mean1)
{
  int gid = blockIdx.x * blockDim.x + threadIdx.x;
  int n = gid >> 6;
  int lane = threadIdx.x & 63;
  if (n >= N_NODES) return;
  int slot = lane >> 2;
  int fq = lane & 3;
  int beg = row_ptr[n], end = row_ptr[n + 1];
  int deg = end - beg;
  float s0 = 0.f, s1 = 0.f, s2 = 0.f, s3 = 0.f, s4 = 0.f, s5 = 0.f, s6 = 0.f, s7 = 0.f;
  int i = beg;
  for (; i + 31 < end; i += 32) {                // 32 neighbors, 2 gathers/lane
    int n0 = csr[i + slot];
    int n1 = csr[i + 16 + slot];
    uint4 a = xb4[n0 * 4 + fq];
    uint4 b = xb4[n1 * 4 + fq];
    s0 += bf_lo(a.x); s1 += bf_hi(a.x); s2 += bf_lo(a.y); s3 += bf_hi(a.y);
    s4 += bf_lo(a.z); s5 += bf_hi(a.z); s6 += bf_lo(a.w); s7 += bf_hi(a.w);
    s0 += bf_lo(b.x); s1 += bf_hi(b.x); s2 += bf_lo(b.y); s3 += bf_hi(b.y);
    s4 += bf_lo(b.z); s5 += bf_hi(b.z); s6 += bf_lo(b.w); s7 += bf_hi(b.w);
  }
  for (; i < end; i += 16) {
    if (i + slot < end) {
      uint4 a = xb4[csr[i + slot] * 4 + fq];
      s0 += bf_lo(a.x); s1 += bf_hi(a.x); s2 += bf_lo(a.y); s3 += bf_hi(a.y);
      s4 += bf_lo(a.z); s5 += bf_hi(a.z); s6 += bf_lo(a.w); s7 += bf_hi(a.w);
    }
  }
#pragma unroll
  for (int off = 4; off <= 32; off <<= 1) {
    s0 += __shfl_xor(s0, off); s1 += __shfl_xor(s1, off);
    s2 += __shfl_xor(s2, off); s3 += __shfl_xor(s3, off);
    s4 += __shfl_xor(s4, off); s5 += __shfl_xor(s5, off);
    s6 += __shfl_xor(s6, off); s7 += __shfl_xor(s7, off);
  }
  if (slot == 0) {
    float invd = (deg > 0) ? 1.f / (float)deg : 0.f;
    uint4 o;
    o.x = pack2bf(s0 * invd, s1 * invd);
    o.y = pack2bf(s2 * invd, s3 * invd);
    o.z = pack2bf(s4 * invd, s5 * invd);
    o.w = pack2bf(s6 * invd, s7 * invd);
    mean1[n * 4 + fq] = o;
  }
}

// layer 2 mean: h1b rows are 128B (8 uint4). lane: slot=(l>>3) in 0..7,
// fq=(l&7). 8 neighbors in flight per instruction, 2x unrolled.
__global__ void __launch_bounds__(256) k_gather2(
    const uint4* __restrict__ hb4, const int* __restrict__ row_ptr,
    const int* __restrict__ csr, uint4* __restrict__ mean2)
{
  int gid = blockIdx.x * blockDim.x + threadIdx.x;
  int n = gid >> 6;
  int lane = threadIdx.x & 63;
  if (n >= N_NODES) return;
  int slot = lane >> 3;
  int fq = lane & 7;
  int beg = row_ptr[n], end = row_ptr[n + 1];
  int deg = end - beg;
  float s0 = 0.f, s1 = 0.f, s2 = 0.f, s3 = 0.f, s4 = 0.f, s5 = 0.f, s6 = 0.f, s7 = 0.f;
  int i = beg;
  for (; i + 15 < end; i += 16) {                // 16 neighbors, 2 gathers/lane
    int n0 = csr[i + slot];
    int n1 = csr[i + 8 + slot];
    uint4 a = hb4[n0 * 8 + fq];
    uint4 b = hb4[n1 * 8 + fq];
    s0 += bf_lo(a.x); s1 += bf_hi(a.x); s2 += bf_lo(a.y); s3 += bf_hi(a.y);
    s4 += bf_lo(a.z); s5 += bf_hi(a.z); s6 += bf_lo(a.w); s7 += bf_hi(a.w);
    s0 += bf_lo(b.x); s1 += bf_hi(b.x); s2 += bf_lo(b.y); s3 += bf_hi(b.y);
    s4 += bf_lo(b.z); s5 += bf_hi(b.z); s6 += bf_lo(b.w); s7 += bf_hi(b.w);
  }
  for (; i < end; i += 8) {
    if (i + slot < end) {
      uint4 a = hb4[csr[i + slot] * 8 + fq];
      s0 += bf_lo(a.x); s1 += bf_hi(a.x); s2 += bf_lo(a.y); s3 += bf_hi(a.y);
      s4 += bf_lo(a.z); s5 += bf_hi(a.z); s6 += bf_lo(a.w); s7 += bf_hi(a.w);
    }
  }
#pragma unroll
  for (int off = 8; off <= 32; off <<= 1) {
    s0 += __shfl_xor(s0, off); s1 += __shfl_xor(s1, off);
    s2 += __shfl_xor(s2, off); s3 += __shfl_xor(s3, off);
    s4 += __shfl_xor(s4, off); s5 += __shfl_xor(s5, off);
    s6 += __shfl_xor(s6, off); s7 += __shfl_xor(s7, off);
  }
  if (slot == 0) {
    float invd = (deg > 0) ? 1.f / (float)deg : 0.f;
    uint4 o;
    o.x = pack2bf(s0 * invd, s1 * invd);
    o.y = pack2bf(s2 * invd, s3 * invd);
    o.z = pack2bf(s4 * invd, s5 * invd);
    o.w = pack2bf(s6 * invd, s7 * invd);
    mean2[n * 8 + fq] = o;
  }
}

// ---------------- MFMA GEMM kernels (wave = 16-node tile) --------------------
// A-frag: lane l holds A[l&15][(l>>4)*8+e], e=0..7 (one 16B load).
// B-frag: lane l holds B[(l>>4)*8+e][l&15]; W stored transposed -> 16B load.
// C/D: lane l, reg r -> row (l>>4)*4+r, col l&15  [verified m89/m91].

// h1 = relu([mean1 | x] * W1 + bl1), K=64
__global__ void __launch_bounds__(256) k_gemm1(
    const ushort* __restrict__ mean1, const ushort* __restrict__ xb,
    const ushort* __restrict__ W1T, const float* __restrict__ bl,
    ushort* __restrict__ h1b)
{
  int wave = (blockIdx.x * blockDim.x + threadIdx.x) >> 6;
  if (wave >= N_TILES) return;
  int lane = threadIdx.x & 63;
  int lc = lane & 15;
  int lg = lane >> 4;
  int n0 = wave * 16;

  bf16x8 bfr[4][2];
#pragma unroll
  for (int j = 0; j < 4; ++j)
#pragma unroll
    for (int kk = 0; kk < 2; ++kk)
      bfr[j][kk] = *(const bf16x8*)(W1T + (j * 16 + lc) * 64 + kk * 32 + lg * 8);

  f32x4 c[4];
#pragma unroll
  for (int j = 0; j < 4; ++j) {
    float b = bl[j * 16 + lc];
    c[j][0] = b; c[j][1] = b; c[j][2] = b; c[j][3] = b;
  }

  bf16x8 a0 = *(const bf16x8*)(mean1 + (n0 + lc) * 32 + lg * 8);
  bf16x8 a1 = *(const bf16x8*)(xb    + (n0 + lc) * 32 + lg * 8);
#pragma unroll
  for (int j = 0; j < 4; ++j) {
    c[j] = __builtin_amdgcn_mfma_f32_16x16x32_bf16(a0, bfr[j][0], c[j], 0, 0, 0);
    c[j] = __builtin_amdgcn_mfma_f32_16x16x32_bf16(a1, bfr[j][1], c[j], 0, 0, 0);
  }

#pragma unroll
  for (int j = 0; j < 4; ++j)
#pragma unroll
    for (int r = 0; r < 4; ++r) {
      int node = n0 + lg * 4 + r;
      h1b[node * 64 + j * 16 + lc] = f2bf(fmaxf(c[j][r], 0.f));
    }
}

// h2 = relu([mean2 | h1] * W2 + bl2); fused u=dot(h2,Wh_lo), v=dot(h2,Wh_hi).
__global__ void __launch_bounds__(256) k_gemm2(
    const ushort* __restrict__ mean2, const ushort* __restrict__ h1b,
    const ushort* __restrict__ W2T, const float* __restrict__ bl,
    const float* __restrict__ Wh, float* __restrict__ u, float* __restrict__ v)
{
  int wave = (blockIdx.x * blockDim.x + threadIdx.x) >> 6;
  if (wave >= N_TILES) return;
  int lane = threadIdx.x & 63;
  int lc = lane & 15;
  int lg = lane >> 4;
  int n0 = wave * 16;

  bf16x8 bfr[4][4];
#pragma unroll
  for (int j = 0; j < 4; ++j)
#pragma unroll
    for (int kk = 0; kk < 4; ++kk)
      bfr[j][kk] = *(const bf16x8*)(W2T + (j * 16 + lc) * 128 + kk * 32 + lg * 8);

  f32x4 c[4];
#pragma unroll
  for (int j = 0; j < 4; ++j) {
    float b = bl[j * 16 + lc];
    c[j][0] = b; c[j][1] = b; c[j][2] = b; c[j][3] = b;
  }

  bf16x8 a0 = *(const bf16x8*)(mean2 + (n0 + lc) * 64 + lg * 8);
  bf16x8 a1 = *(const bf16x8*)(mean2 + (n0 + lc) * 64 + 32 + lg * 8);
  bf16x8 a2 = *(const bf16x8*)(h1b   + (n0 + lc) * 64 + lg * 8);
  bf16x8 a3 = *(const bf16x8*)(h1b   + (n0 + lc) * 64 + 32 + lg * 8);
#pragma unroll
  for (int j = 0; j < 4; ++j) {
    c[j] = __builtin_amdgcn_mfma_f32_16x16x32_bf16(a0, bfr[j][0], c[j], 0, 0, 0);
    c[j] = __builtin_amdgcn_mfma_f32_16x16x32_bf16(a1, bfr[j][1], c[j], 0, 0, 0);
    c[j] = __builtin_amdgcn_mfma_f32_16x16x32_bf16(a2, bfr[j][2], c[j], 0, 0, 0);
    c[j] = __builtin_amdgcn_mfma_f32_16x16x32_bf16(a3, bfr[j][3], c[j], 0, 0, 0);
  }

  float pu0 = 0.f, pu1 = 0.f, pu2 = 0.f, pu3 = 0.f;
  float pv0 = 0.f, pv1 = 0.f, pv2 = 0.f, pv3 = 0.f;
#pragma unroll
  for (int j = 0; j < 4; ++j) {
    float wu = Wh[j * 16 + lc];
    float wv = Wh[64 + j * 16 + lc];
    float r0 = fmaxf(c[j][0], 0.f), r1 = fmaxf(c[j][1], 0.f);
    float r2 = fmaxf(c[j][2], 0.f), r3 = fmaxf(c[j][3], 0.f);
    pu0 = fmaf(r0, wu, pu0); pv0 = fmaf(r0, wv, pv0);
    pu1 = fmaf(r1, wu, pu1); pv1 = fmaf(r1, wv, pv1);
    pu2 = fmaf(r2, wu, pu2); pv2 = fmaf(r2, wv, pv2);
    pu3 = fmaf(r3, wu, pu3); pv3 = fmaf(r3, wv, pv3);
  }
#pragma unroll
  for (int off = 1; off <= 8; off <<= 1) {
    pu0 += __shfl_xor(pu0, off); pv0 += __shfl_xor(pv0, off);
    pu1 += __shfl_xor(pu1, off); pv1 += __shfl_xor(pv1, off);
    pu2 += __shfl_xor(pu2, off); pv2 += __shfl_xor(pv2, off);
    pu3 += __shfl_xor(pu3, off); pv3 += __shfl_xor(pv3, off);
  }
  if (lc == 0) {
    int node = n0 + lg * 4;
    u[node]     = pu0; v[node]     = pv0;
    u[node + 1] = pu1; v[node + 1] = pv1;
    u[node + 2] = pu2; v[node + 2] = pv2;
    u[node + 3] = pu3; v[node + 3] = pv3;
  }
}

// ---------------- edge scorer: table lookup only ----------------

__global__ void __launch_bounds__(256) k_edge_lite(
    const int* __restrict__ pairs, const float* __restrict__ u,
    const float* __restrict__ v, const float* __restrict__ bh,
    float* __restrict__ out)
{
  int e = blockIdx.x * blockDim.x + threadIdx.x;
  if (e < N_PAIRS) {
    int sN = pairs[2 * e];
    int dN = pairs[2 * e + 1];
    out[e] = u[sN] + v[dN] + bh[0];
  }
}

// ---------------- launch ----------------

extern "C" void kernel_launch(void* const* d_in, const int* in_sizes, int n_in,
                              void* d_out, int out_size, void* d_ws, size_t ws_size,
                              hipStream_t stream)
{
  const float* x   = (const float*)d_in[0];
  const int*   ei  = (const int*)d_in[1];
  const int* pairs = (const int*)d_in[2];
  const float* Wl1 = (const float*)d_in[3];
  const float* bl1 = (const float*)d_in[4];
  const float* Wr1 = (const float*)d_in[5];
  const float* Wl2 = (const float*)d_in[6];
  const float* bl2 = (const float*)d_in[7];
  const float* Wr2 = (const float*)d_in[8];
  const float* Wh  = (const float*)d_in[9];
  const float* bh  = (const float*)d_in[10];
  float* out = (float*)d_out;

  const int* src = ei;             // edge_index[0]
  const int* dst = ei + N_EDGES;   // edge_index[1]

  char* p = (char*)d_ws;
  auto alloc = [&](size_t bytes) {
    char* r = p;
    p += (bytes + 255) & ~(size_t)255;
    return r;
  };
  int*    bucket_cnt  = (int*)alloc(256 * 4);
  int*    bucket_base = (int*)alloc(257 * 4);
  int*    bucket_woff = (int*)alloc(256 * 4);
  int*    bucket_data = (int*)alloc((size_t)N_EDGES * 4);   // reused as mean2
  int*    csr         = (int*)alloc((size_t)N_EDGES * 4);
  int*    row_ptr     = (int*)alloc((size_t)(N_NODES + 1) * 4);
  ushort* xb          = (ushort*)alloc((size_t)N_NODES * 32 * 2);
  ushort* h1b         = (ushort*)alloc((size_t)N_NODES * 64 * 2);
  ushort* mean1       = (ushort*)alloc((size_t)N_NODES * 32 * 2);
  ushort* W1T         = (ushort*)alloc(64 * 64 * 2);
  ushort* W2T         = (ushort*)alloc(64 * 128 * 2);
  float*  uu          = (float*)alloc((size_t)N_NODES * 4);
  float*  vv          = (float*)alloc((size_t)N_NODES * 4);
  ushort* mean2       = (ushort*)bucket_data;   // dead after k_bucket_csr; 12.8MB

  k_zero<<<1, 256, 0, stream>>>(bucket_cnt, NBUCK);
  k_bucket_count<<<NCHB, 256, 0, stream>>>(dst, bucket_cnt);
  k_bucket_scan<<<1, 256, 0, stream>>>(bucket_cnt, bucket_base, bucket_woff);
  k_binning<<<NCHB, 256, 0, stream>>>(src, dst, bucket_woff, bucket_data);
  k_bucket_csr<<<NBUCK, 512, 0, stream>>>(bucket_base, bucket_data, csr, row_ptr);

  k_cvt_bf16<<<(N_NODES * 32 + 255) / 256, 256, 0, stream>>>(x, xb, N_NODES * 32);
  k_prep_w<<<32, 256, 0, stream>>>(Wl1, Wr1, Wl2, Wr2, W1T, W2T);

  k_gather1<<<(N_NODES * 64) / 256, 256, 0, stream>>>(
      (const uint4*)xb, row_ptr, csr, (uint4*)mean1);
  k_gemm1<<<(N_TILES * 64 + 255) / 256, 256, 0, stream>>>(
      mean1, xb, W1T, bl1, h1b);
  k_gather2<<<(N_NODES * 64) / 256, 256, 0, stream>>>(
      (const uint4*)h1b, row_ptr, csr, (uint4*)mean2);
  k_gemm2<<<(N_TILES * 64 + 255) / 256, 256, 0, stream>>>(
      mean2, h1b, W2T, bl2, Wh, uu, vv);
  k_edge_lite<<<(N_PAIRS + 255) / 256, 256, 0, stream>>>(pairs, uu, vv, bh, out);
}